// Round 7
// baseline (806.735 us; speedup 1.0000x reference)
//
#include <hip/hip_runtime.h>
#include <hip/hip_bf16.h>

// ---------------------------------------------------------------------------
// Problem constants
// ---------------------------------------------------------------------------
#define N0 100000
#define E0C 1600000
#define N1 100000
#define E1C 1600000
#define GCONST 512
#define F0C 93
#define F1C 43
#define OC0 (F0C * 10)   // 930
#define OC1 (F1C * 10)   // 430
#define BN_EPS 1e-5f
#define NBKT 391         // ceil(100000 / 256) buckets for CSR fill
#define SLAB 6016        // staging slab per bucket (avg 4092, sigma~64 -> +30 sigma)

typedef __attribute__((ext_vector_type(8))) short short8;
typedef __attribute__((ext_vector_type(4))) float floatx4;

static __device__ __forceinline__ unsigned short f2bf(float f) {
    unsigned u = __float_as_uint(f);
    unsigned r = (u + 0x7FFF + ((u >> 16) & 1)) >> 16;   // RNE
    return (unsigned short)r;
}
static __device__ __forceinline__ float bf2f(unsigned short u) {
    return __uint_as_float(((unsigned)u) << 16);
}
static __device__ __forceinline__ void split_bf(float v, unsigned short& h, unsigned short& l) {
    h = f2bf(v);
    l = f2bf(v - bf2f(h));
}

// ---------------------------------------------------------------------------
// misc: find_starts [0,6) + slab cursor init [6]
// ---------------------------------------------------------------------------
__global__ __launch_bounds__(256) void misc_kernel(const int* __restrict__ bat0,
                                                   const int* __restrict__ bat1,
                                                   int* __restrict__ st0,
                                                   int* __restrict__ st1,
                                                   int* __restrict__ bcur2) {
    int bid = blockIdx.x;
    int t = threadIdx.x;
    if (bid < 6) {
        int branch = bid / 3;
        const int* batch = branch ? bat1 : bat0;
        int* starts = branch ? st1 : st0;
        int g = (bid % 3) * 256 + t;
        if (g > GCONST) return;
        if (g == GCONST) { starts[GCONST] = N0; return; }
        int lo = 0, hi = N0;
        while (lo < hi) {
            int mid = (lo + hi) >> 1;
            if (batch[mid] < g) lo = mid + 1; else hi = mid;
        }
        starts[g] = lo;
    } else {
        for (int i = t; i < 1024; i += 256) {
            if (i < NBKT) bcur2[i] = i * SLAB;
            else if (i >= 512 && i < 512 + NBKT) bcur2[i] = (i - 512) * SLAB;
        }
    }
}

// ---------------------------------------------------------------------------
// edge_bucket2: edges(b0) [0,782) | edges(b1) [782,1564) | wt_prep [1564,3612)
//               | p0 pad [3612,3732) | p1 pad [3732,3804)
// ---------------------------------------------------------------------------
__global__ __launch_bounds__(256) void edge_bucket2_kernel(const int* __restrict__ ei0,
                                                           const int* __restrict__ ei1,
                                                           int E, int* __restrict__ bcur2,
                                                           int2* __restrict__ st0,
                                                           int2* __restrict__ st1,
                                                           const float* __restrict__ Wc1,
                                                           const float* __restrict__ Wc2,
                                                           const float* __restrict__ Wc3,
                                                           const float* __restrict__ Wc4,
                                                           unsigned short* __restrict__ Ta0,
                                                           unsigned short* __restrict__ Tb0,
                                                           unsigned short* __restrict__ Ta1,
                                                           unsigned short* __restrict__ Tb1,
                                                           unsigned short* __restrict__ p0h,
                                                           unsigned short* __restrict__ p0l,
                                                           unsigned short* __restrict__ p1h,
                                                           unsigned short* __restrict__ p1l) {
    int bid = blockIdx.x;
    int t = threadIdx.x;
    if (bid < 1564) {
        int branch = bid >= 782;
        int blk = branch ? bid - 782 : bid;
        const int* ei = branch ? ei1 : ei0;
        int* bcur = bcur2 + branch * 512;
        int2* staging = branch ? st1 : st0;
        __shared__ int hist[NBKT];
        __shared__ int gbase[NBKT];
        for (int i = t; i < NBKT; i += 256) hist[i] = 0;
        __syncthreads();
        int base = blk * 2048;
        int srcv[8], dstv[8];
#pragma unroll
        for (int i = 0; i < 8; ++i) {
            int e = base + i * 256 + t;
            if (e < E) { srcv[i] = ei[e]; dstv[i] = ei[E + e]; }
            else dstv[i] = -1;
        }
#pragma unroll
        for (int i = 0; i < 8; ++i)
            if (dstv[i] >= 0) atomicAdd(&hist[dstv[i] >> 8], 1);
        __syncthreads();
        for (int i = t; i < NBKT; i += 256) {
            int c = hist[i];
            gbase[i] = c ? atomicAdd(&bcur[i], c) : 0;
            hist[i] = 0;   // reuse as local cursor
        }
        __syncthreads();
#pragma unroll
        for (int i = 0; i < 8; ++i) {
            if (dstv[i] >= 0) {
                int b = dstv[i] >> 8;
                int lofs = atomicAdd(&hist[b], 1);
                staging[gbase[b] + lofs] = make_int2(srcv[i], dstv[i]);
            }
        }
    } else if (bid < 3612) {
        int idx = bid - 1564;
        int cfg = idx >> 9;
        int c = (idx & 511) * 2 + (t >> 7);
        int k = t & 127;
        const float* W; unsigned short* T; int OCr, Fr, KP, RB;
        switch (cfg) {
            case 0:  W = Wc1; T = Ta0; OCr = 93;  Fr = 93; KP = 96; RB = 96;   break;
            case 1:  W = Wc2; T = Tb0; OCr = 930; Fr = 93; KP = 96; RB = 1024; break;
            case 2:  W = Wc3; T = Ta1; OCr = 43;  Fr = 43; KP = 64; RB = 48;   break;
            default: W = Wc4; T = Tb1; OCr = 430; Fr = 43; KP = 64; RB = 512;  break;
        }
        if (c >= RB || k >= KP) return;
        unsigned short v = 0;
        if (c < OCr && k < Fr) v = f2bf(W[(size_t)k * OCr + c]);
        T[(size_t)c * KP + k] = v;
    } else if (bid < 3732) {
        int i = (bid - 3612) * 256 + t;
        if (i >= GCONST * 60) return;
        int g = i / 60, c = 1860 + (i - g * 60);
        p0h[(size_t)g * 1920 + c] = 0;
        p0l[(size_t)g * 1920 + c] = 0;
    } else {
        int i = (bid - 3732) * 256 + t;
        if (i >= GCONST * 36) return;
        int g = i / 36, c = 860 + (i - g * 36);
        p1h[(size_t)g * 896 + c] = 0;
        p1l[(size_t)g * 896 + c] = 0;
    }
}

// ---------------------------------------------------------------------------
// bucket_scan2: recover bucket counts from slab cursors, exclusive scan
// ---------------------------------------------------------------------------
__global__ __launch_bounds__(512) void bucket_scan2_kernel(const int* __restrict__ bcur2,
                                                           int* __restrict__ bbase2) {
    const int* bcur = bcur2 + blockIdx.x * 512;
    int* bbase = bbase2 + blockIdx.x * 512;
    __shared__ int sh[512];
    int t = threadIdx.x;
    int cnt = (t < NBKT) ? bcur[t] - t * SLAB : 0;
    sh[t] = cnt;
    __syncthreads();
    for (int o = 1; o < 512; o <<= 1) {
        int add = (t >= o) ? sh[t - o] : 0;
        __syncthreads();
        sh[t] += add;
        __syncthreads();
    }
    if (t <= NBKT) bbase[t] = sh[t] - cnt;   // exclusive; t==NBKT -> total==E
}

// per-bucket fused {LDS histogram -> scan -> rowptr -> col scatter} from slab
static __device__ __forceinline__ void csr_build_dev(int b, const int2* __restrict__ staging,
                                                     const int* __restrict__ bcur,
                                                     const int* __restrict__ bbase, int N,
                                                     int* __restrict__ rowptr,
                                                     int* __restrict__ col) {
    __shared__ int h[256];
    __shared__ int sc[256];
    int t = threadIdx.x;
    int sl = b * SLAB;
    int se = bcur[b];
    int go = bbase[b];
    h[t] = 0;
    __syncthreads();
    for (int i = sl + t; i < se; i += 256)
        atomicAdd(&h[staging[i].y & 255], 1);
    __syncthreads();
    int v = h[t];
    sc[t] = v;
    __syncthreads();
    for (int o = 1; o < 256; o <<= 1) {
        int add = (t >= o) ? sc[t - o] : 0;
        __syncthreads();
        sc[t] += add;
        __syncthreads();
    }
    int ex = go + (sc[t] - v);
    int node = (b << 8) + t;
    if (node <= N) rowptr[node] = ex;
    __syncthreads();
    sc[t] = ex;                          // reuse as cursor
    __syncthreads();
    for (int i = sl + t; i < se; i += 256) {
        int2 ed = staging[i];
        int pos = atomicAdd(&sc[ed.y & 255], 1);
        col[pos] = ed.x;
    }
}

// ---------------------------------------------------------------------------
// MLP weight transpose + hi/lo bf16 split (device body; fused into f1)
// ---------------------------------------------------------------------------
static __device__ __forceinline__ void wsplit_dev(int k0, int c0,
                                                  const float* __restrict__ W,
                                                  unsigned short* __restrict__ Th,
                                                  unsigned short* __restrict__ Tl,
                                                  int K, int N, int KP) {
    __shared__ float tile[32][33];
    int tx = threadIdx.x & 31, ty = threadIdx.x >> 5;
    for (int r = ty; r < 32; r += 8) {
        int k = k0 + r;
        tile[r][tx] = (k < K) ? W[(size_t)k * N + c0 + tx] : 0.f;
    }
    __syncthreads();
    for (int r = ty; r < 32; r += 8) {
        int c = c0 + r;
        float v = tile[tx][r];
        unsigned short h, l;
        split_bf(v, h, l);
        Th[(size_t)c * KP + k0 + tx] = h;
        Tl[(size_t)c * KP + k0 + tx] = l;
    }
}

// ---------------------------------------------------------------------------
// chunked gather-aggregate: one wave per node per 64B feature chunk.
//   bid = chunk*NB + nb  (temporal feature blocking: concurrent blocks share a
//   6.4MB column slab -> L2-resident, vs 19.2MB full table at 45% hit).
//   CH=4 lanes per chunk row, GR=16 edges in flight per wave instruction.
// ---------------------------------------------------------------------------
template<int KP>
static __device__ __forceinline__ void gather_chunk_dev(int bid, int NB,
                                                        unsigned short* __restrict__ t,
                                                        const unsigned short* __restrict__ x,
                                                        const int* __restrict__ rowptr,
                                                        const int* __restrict__ col, int N) {
    int chunk = bid / NB;
    int nb = bid - chunk * NB;
    int wave = threadIdx.x >> 6, lane = threadIdx.x & 63;
    int node = nb * 4 + wave;
    if (node >= N) return;
    int g = lane >> 2;                  // 16 edge groups
    int c = lane & 3;                   // 4 x 16B within the 64B chunk
    int eoff = chunk * 32 + c * 8;      // element offset
    int s = rowptr[node], e = rowptr[node + 1];
    float acc[8] = {0.f, 0.f, 0.f, 0.f, 0.f, 0.f, 0.f, 0.f};
    int j = s - 1 + g;                  // j == s-1 -> self row (group 0)
    int src0 = node;
    if (j >= s && j < e) src0 = col[j];
    while (j < e) {
        int jb = j + 16;
        int jc = jb + 16;
        int srcb = (jb < e) ? col[jb] : 0;
        int srcc = (jc < e) ? col[jc] : 0;
        short8 v0 = *(const short8*)(x + (size_t)src0 * KP + eoff);
#pragma unroll
        for (int i = 0; i < 8; ++i) acc[i] += bf2f((unsigned short)v0[i]);
        if (jb < e) {
            short8 v1 = *(const short8*)(x + (size_t)srcb * KP + eoff);
#pragma unroll
            for (int i = 0; i < 8; ++i) acc[i] += bf2f((unsigned short)v1[i]);
        }
        j = jc; src0 = srcc;
    }
#pragma unroll
    for (int o = 4; o < 64; o <<= 1) {
#pragma unroll
        for (int i = 0; i < 8; ++i) acc[i] += __shfl_xor(acc[i], o);
    }
    if (lane < 4) {
        short8 o8;
#pragma unroll
        for (int i = 0; i < 8; ++i) o8[i] = (short)f2bf(acc[i]);
        *(short8*)(t + (size_t)node * KP + chunk * 32 + lane * 8) = o8;
    }
}

// conv1 via MFMA: y = relu(t @ W + b), bf16 [N][KP]
template<int KP, int KS, int NT>
static __device__ __forceinline__ void conv1_dev(int nb, const unsigned short* __restrict__ t,
                                                 const unsigned short* __restrict__ Wt,
                                                 const float* __restrict__ bias,
                                                 unsigned short* __restrict__ y,
                                                 int NC, int N) {
    int wave = threadIdx.x >> 6, lane = threadIdx.x & 63;
    int quad = lane >> 4, l15 = lane & 15;
    int r0 = (nb * 4 + wave) * 16;
    const short8 z8 = {0, 0, 0, 0, 0, 0, 0, 0};
    short8 a[KS];
    int arow = r0 + l15;
#pragma unroll
    for (int ks = 0; ks < KS; ++ks)
        a[ks] = (arow < N) ? *(const short8*)(t + (size_t)arow * KP + ks * 32 + quad * 8) : z8;
#pragma unroll
    for (int nt = 0; nt < NT; ++nt) {
        int colb = nt * 16 + l15;
        floatx4 c = {0.f, 0.f, 0.f, 0.f};
#pragma unroll
        for (int ks = 0; ks < KS; ++ks) {
            short8 b = *(const short8*)(Wt + (size_t)colb * KP + ks * 32 + quad * 8);
            c = __builtin_amdgcn_mfma_f32_16x16x32_bf16(a[ks], b, c, 0, 0, 0);
        }
        float bc = (colb < NC) ? bias[colb] : 0.f;
#pragma unroll
        for (int r = 0; r < 4; ++r) {
            int row = r0 + quad * 4 + r;
            if (row < N) {
                float o = fmaxf(c[r] + bc, 0.f);
                y[(size_t)row * KP + colb] = f2bf(o);
            }
        }
    }
}

// conv2 + relu + mean/max pool, epilogue emits hi/lo bf16 pooled rows
template<int KP, int KS>
static __device__ __forceinline__ void conv2_pool_dev(int cb, int g,
                                                      const unsigned short* __restrict__ t,
                                                      const unsigned short* __restrict__ Wt,
                                                      const float* __restrict__ bias,
                                                      const int* __restrict__ starts,
                                                      unsigned short* __restrict__ ph,
                                                      unsigned short* __restrict__ pl,
                                                      int OC, int KPad) {
    int wave = threadIdx.x >> 6, lane = threadIdx.x & 63;
    int quad = lane >> 4, l15 = lane & 15;
    int cw0 = cb * 256 + wave * 64;
    short8 bfr[4][KS];
    float bs[4];
#pragma unroll
    for (int ti = 0; ti < 4; ++ti) {
        int colb = cw0 + ti * 16 + l15;
#pragma unroll
        for (int ks = 0; ks < KS; ++ks)
            bfr[ti][ks] = *(const short8*)(Wt + (size_t)colb * KP + ks * 32 + quad * 8);
        bs[ti] = (colb < OC) ? bias[colb] : 0.f;
    }
    int s = starts[g], e = starts[g + 1];
    float sum[4] = {0.f, 0.f, 0.f, 0.f};
    float mx[4]  = {0.f, 0.f, 0.f, 0.f};
    const short8 z8 = {0, 0, 0, 0, 0, 0, 0, 0};
    for (int ns = s; ns < e; ns += 16) {
        short8 a[KS];
        int arow = ns + l15;
        bool av = arow < e;
#pragma unroll
        for (int ks = 0; ks < KS; ++ks)
            a[ks] = av ? *(const short8*)(t + (size_t)arow * KP + ks * 32 + quad * 8) : z8;
        int rbase = ns + quad * 4;
#pragma unroll
        for (int ti = 0; ti < 4; ++ti) {
            floatx4 c = {0.f, 0.f, 0.f, 0.f};
#pragma unroll
            for (int ks = 0; ks < KS; ++ks)
                c = __builtin_amdgcn_mfma_f32_16x16x32_bf16(a[ks], bfr[ti][ks], c, 0, 0, 0);
#pragma unroll
            for (int r = 0; r < 4; ++r) {
                float o = fmaxf(c[r] + bs[ti], 0.f);
                if (rbase + r < e) {
                    sum[ti] += o;
                    mx[ti] = fmaxf(mx[ti], o);
                }
            }
        }
    }
    int cnt = e - s;
    float rc = 1.f / (float)(cnt > 0 ? cnt : 1);
#pragma unroll
    for (int ti = 0; ti < 4; ++ti) {
        float sv = sum[ti], mv = mx[ti];
        sv += __shfl_down(sv, 32);
        mv = fmaxf(mv, __shfl_down(mv, 32));
        sv += __shfl_down(sv, 16);
        mv = fmaxf(mv, __shfl_down(mv, 16));
        if (lane < 16) {
            int colb = cw0 + ti * 16 + l15;
            if (colb < OC) {
                size_t base = (size_t)g * (size_t)KPad;
                unsigned short h, l;
                split_bf(sv * rc, h, l);
                ph[base + colb] = h; pl[base + colb] = l;
                split_bf(mv, h, l);
                ph[base + OC + colb] = h; pl[base + OC + colb] = l;
            }
        }
    }
}

// split-bf16 ("bf16x3") MFMA GEMM tile: C = A @ B^T(+bias), fp32-equivalent.
// MODE 0: relu, write hi/lo bf16.  MODE 1: fp32.  MODE 2: relu, fp32.
template<int MODE>
static __device__ __forceinline__ void gemm3x_dev(int bx, int by, int NBX,
                                                  const unsigned short* __restrict__ Ah,
                                                  const unsigned short* __restrict__ Al,
                                                  const unsigned short* __restrict__ Bh,
                                                  const unsigned short* __restrict__ Bl,
                                                  const float* __restrict__ bias,
                                                  float* __restrict__ Cf,
                                                  unsigned short* __restrict__ Ch,
                                                  unsigned short* __restrict__ Cl,
                                                  int KP) {
    int wave = threadIdx.x >> 6, lane = threadIdx.x & 63;
    int quad = lane >> 4, l15 = lane & 15;
    int r0 = by * 32 + (wave & 1) * 16;
    int c0 = bx * 64 + (wave >> 1) * 32;
    int Ncols = NBX * 64;
    floatx4 acc0 = {0.f, 0.f, 0.f, 0.f};
    floatx4 acc1 = {0.f, 0.f, 0.f, 0.f};
    const unsigned short* arh = Ah + (size_t)(r0 + l15) * KP;
    const unsigned short* arl = Al + (size_t)(r0 + l15) * KP;
    const unsigned short* b0h = Bh + (size_t)(c0 + l15) * KP;
    const unsigned short* b0l = Bl + (size_t)(c0 + l15) * KP;
    const unsigned short* b1h = Bh + (size_t)(c0 + 16 + l15) * KP;
    const unsigned short* b1l = Bl + (size_t)(c0 + 16 + l15) * KP;
    for (int k0 = 0; k0 < KP; k0 += 128) {
        short8 ah[4], al[4];
#pragma unroll
        for (int q = 0; q < 4; ++q) {
            ah[q] = *(const short8*)(arh + k0 + q * 32 + quad * 8);
            al[q] = *(const short8*)(arl + k0 + q * 32 + quad * 8);
        }
#pragma unroll
        for (int q = 0; q < 4; ++q) {
            short8 bh = *(const short8*)(b0h + k0 + q * 32 + quad * 8);
            short8 bl = *(const short8*)(b0l + k0 + q * 32 + quad * 8);
            acc0 = __builtin_amdgcn_mfma_f32_16x16x32_bf16(ah[q], bh, acc0, 0, 0, 0);
            acc0 = __builtin_amdgcn_mfma_f32_16x16x32_bf16(al[q], bh, acc0, 0, 0, 0);
            acc0 = __builtin_amdgcn_mfma_f32_16x16x32_bf16(ah[q], bl, acc0, 0, 0, 0);
            bh = *(const short8*)(b1h + k0 + q * 32 + quad * 8);
            bl = *(const short8*)(b1l + k0 + q * 32 + quad * 8);
            acc1 = __builtin_amdgcn_mfma_f32_16x16x32_bf16(ah[q], bh, acc1, 0, 0, 0);
            acc1 = __builtin_amdgcn_mfma_f32_16x16x32_bf16(al[q], bh, acc1, 0, 0, 0);
            acc1 = __builtin_amdgcn_mfma_f32_16x16x32_bf16(ah[q], bl, acc1, 0, 0, 0);
        }
    }
    int col0 = c0 + l15, col1 = c0 + 16 + l15;
    float bc0 = bias[col0], bc1 = bias[col1];
#pragma unroll
    for (int r = 0; r < 4; ++r) {
        int row = r0 + quad * 4 + r;
        float v0 = acc0[r] + bc0;
        float v1 = acc1[r] + bc1;
        if (MODE != 1) { v0 = fmaxf(v0, 0.f); v1 = fmaxf(v1, 0.f); }
        if (MODE == 0) {
            unsigned short h, l;
            split_bf(v0, h, l);
            Ch[(size_t)row * Ncols + col0] = h; Cl[(size_t)row * Ncols + col0] = l;
            split_bf(v1, h, l);
            Ch[(size_t)row * Ncols + col1] = h; Cl[(size_t)row * Ncols + col1] = l;
        } else {
            Cf[(size_t)row * Ncols + col0] = v0;
            Cf[(size_t)row * Ncols + col1] = v1;
        }
    }
}

// fused batchnorm (stats + apply, one block per column; 512 rows, 512 cols)
static __device__ __forceinline__ void bn_dev(int c, const float* __restrict__ p,
                                              const float* __restrict__ gamma,
                                              const float* __restrict__ beta,
                                              float* __restrict__ outp,
                                              unsigned short* __restrict__ oh,
                                              unsigned short* __restrict__ ol) {
    __shared__ float ls[256], ls2[256];
    int t = threadIdx.x;
    float v0 = p[(size_t)t * 512 + c];
    float v1 = p[(size_t)(t + 256) * 512 + c];
    ls[t] = v0 + v1;
    ls2[t] = v0 * v0 + v1 * v1;
    __syncthreads();
    for (int st = 128; st > 0; st >>= 1) {
        if (t < st) { ls[t] += ls[t + st]; ls2[t] += ls2[t + st]; }
        __syncthreads();
    }
    if (t == 0) {
        float m = ls[0] / 512.f;
        float var = ls2[0] / 512.f - m * m;
        ls[0] = m;
        ls2[0] = 1.f / sqrtf(var + BN_EPS);
    }
    __syncthreads();
    float m = ls[0], iv = ls2[0];
    float g = gamma[c], b = beta[c];
    float w0 = g * (v0 - m) * iv + b;
    float w1 = g * (v1 - m) * iv + b;
    outp[(size_t)t * 512 + c] = w0;
    outp[(size_t)(t + 256) * 512 + c] = w1;
    unsigned short h, l;
    split_bf(w0, h, l);
    oh[(size_t)t * 512 + c] = h; ol[(size_t)t * 512 + c] = l;
    split_bf(w1, h, l);
    oh[(size_t)(t + 256) * 512 + c] = h; ol[(size_t)(t + 256) * 512 + c] = l;
}

// head2: z[row][0..1] = h[row][0..255] @ w2[256][2] + b2. Wave per row.
static __device__ __forceinline__ void head2_dev(int nb, const float* __restrict__ h,
                                                 const float* __restrict__ w2,
                                                 const float* __restrict__ b2,
                                                 float* __restrict__ z, int M) {
    int wave = threadIdx.x >> 6, lane = threadIdx.x & 63;
    int row = nb * 4 + wave;
    if (row >= M) return;
    float4 hv = *(const float4*)(h + (size_t)row * 256 + lane * 4);
    const float* wp = w2 + lane * 8;
    float s0 = hv.x * wp[0] + hv.y * wp[2] + hv.z * wp[4] + hv.w * wp[6];
    float s1 = hv.x * wp[1] + hv.y * wp[3] + hv.z * wp[5] + hv.w * wp[7];
#pragma unroll
    for (int offd = 32; offd >= 1; offd >>= 1) {
        s0 += __shfl_down(s0, offd);
        s1 += __shfl_down(s1, offd);
    }
    if (lane == 0) {
        z[(size_t)row * 2 + 0] = s0 + b2[0];
        z[(size_t)row * 2 + 1] = s1 + b2[1];
    }
}

// ---------------------------------------------------------------------------
// fused stage kernels
// ---------------------------------------------------------------------------

// f0: csr_build(both) + tobf16(both)
__global__ __launch_bounds__(256) void f0_kernel(const int2* __restrict__ st0,
                                                 const int2* __restrict__ st1,
                                                 const int* __restrict__ bcur2,
                                                 const int* __restrict__ bbase2,
                                                 int* __restrict__ rp0, int* __restrict__ rp1,
                                                 int* __restrict__ c0, int* __restrict__ c1,
                                                 unsigned short* __restrict__ xb0,
                                                 const float* __restrict__ x0,
                                                 unsigned short* __restrict__ xb1,
                                                 const float* __restrict__ x1) {
    int bid = blockIdx.x;
    if (bid < 2 * NBKT) {
        int branch = bid >= NBKT;
        csr_build_dev(branch ? bid - NBKT : bid,
                      branch ? st1 : st0,
                      bcur2 + branch * 512, bbase2 + branch * 512, N0,
                      branch ? rp1 : rp0, branch ? c1 : c0);
    } else if (bid < 2 * NBKT + 50000) {
        int b = bid - 2 * NBKT;
        int node = b * 2 + (threadIdx.x >> 7);
        int f = threadIdx.x & 127;
        if (node < N0 && f < 96)
            xb0[(size_t)node * 96 + f] = (f < 93) ? f2bf(x0[(size_t)node * 93 + f]) : (unsigned short)0;
    } else {
        int b = bid - 2 * NBKT - 50000;
        int node = b * 4 + (threadIdx.x >> 6);
        int f = threadIdx.x & 63;
        if (node < N1)
            xb1[(size_t)node * 64 + f] = (f < 43) ? f2bf(x1[(size_t)node * 43 + f]) : (unsigned short)0;
    }
}

// f1: gather-x(b0) chunked [0,75000) + wsplit of all 6 MLP weights [4096]
__global__ __launch_bounds__(256) void f1_kernel(unsigned short* __restrict__ tb,
                                                 const unsigned short* __restrict__ xb0,
                                                 const int* __restrict__ rowptr0,
                                                 const int* __restrict__ col0,
                                                 const float* g0_w1, const float* g0_w2,
                                                 const float* f0_w1,
                                                 const float* g1_w1, const float* g1_w2,
                                                 const float* f1_w1,
                                                 unsigned short* bt1h0, unsigned short* bt1l0,
                                                 unsigned short* bt2h0, unsigned short* bt2l0,
                                                 unsigned short* bt3h0, unsigned short* bt3l0,
                                                 unsigned short* bt1h1, unsigned short* bt1l1,
                                                 unsigned short* bt2h1, unsigned short* bt2l1,
                                                 unsigned short* bt3h1, unsigned short* bt3l1) {
    int bid = blockIdx.x;
    if (bid < 75000) {
        gather_chunk_dev<96>(bid, 25000, tb, xb0, rowptr0, col0, N0);
        return;
    }
    int w = bid - 75000;
    if (w < 1920)      wsplit_dev((w % 60) * 32, (w / 60) * 32, g0_w1, bt1h0, bt1l0, 1860, 1024, 1920);
    else if (w < 2432) { w -= 1920; wsplit_dev((w % 32) * 32, (w / 32) * 32, g0_w2, bt2h0, bt2l0, 1024, 512, 1024); }
    else if (w < 2560) { w -= 2432; wsplit_dev((w % 16) * 32, (w / 16) * 32, f0_w1, bt3h0, bt3l0, 512, 256, 512); }
    else if (w < 3456) { w -= 2560; wsplit_dev((w % 28) * 32, (w / 28) * 32, g1_w1, bt1h1, bt1l1, 860, 1024, 896); }
    else if (w < 3968) { w -= 3456; wsplit_dev((w % 32) * 32, (w / 32) * 32, g1_w2, bt2h1, bt2l1, 1024, 512, 1024); }
    else               { w -= 3968; wsplit_dev((w % 16) * 32, (w / 16) * 32, f1_w1, bt3h1, bt3l1, 512, 256, 512); }
}

// f2: gather-x(b1) chunked [0,50000) + conv1(b0) [1563]
__global__ __launch_bounds__(256) void f2_kernel(unsigned short* __restrict__ t1,
                                                 const unsigned short* __restrict__ xb1,
                                                 const int* __restrict__ rowptr1,
                                                 const int* __restrict__ col1,
                                                 const unsigned short* __restrict__ tb,
                                                 const unsigned short* __restrict__ wt_a0,
                                                 const float* __restrict__ b_c1,
                                                 unsigned short* __restrict__ yb) {
    int bid = blockIdx.x;
    if (bid < 50000)
        gather_chunk_dev<64>(bid, 25000, t1, xb1, rowptr1, col1, N1);
    else
        conv1_dev<96, 3, 6>(bid - 50000, tb, wt_a0, b_c1, yb, 93, N0);
}

// f3: gather-y(b0) chunked [0,75000) + conv1(b1) [1563]
__global__ __launch_bounds__(256) void f3_kernel(unsigned short* __restrict__ tb,
                                                 const unsigned short* __restrict__ yb,
                                                 const int* __restrict__ rowptr0,
                                                 const int* __restrict__ col0,
                                                 const unsigned short* __restrict__ t1,
                                                 const unsigned short* __restrict__ wt_a1,
                                                 const float* __restrict__ b_c3,
                                                 unsigned short* __restrict__ y1) {
    int bid = blockIdx.x;
    if (bid < 75000)
        gather_chunk_dev<96>(bid, 25000, tb, yb, rowptr0, col0, N0);
    else
        conv1_dev<64, 2, 3>(bid - 75000, t1, wt_a1, b_c3, y1, 43, N1);
}

// f4: gather-y(b1) chunked standalone
__global__ __launch_bounds__(256) void f4_kernel(unsigned short* __restrict__ t1,
                                                 const unsigned short* __restrict__ y1,
                                                 const int* __restrict__ rowptr1,
                                                 const int* __restrict__ col1) {
    gather_chunk_dev<64>(blockIdx.x, 25000, t1, y1, rowptr1, col1, N1);
}

// f5: conv2_pool(b0) [2048] + conv2_pool(b1) [1024], XCD-coherent graph mapping
__global__ __launch_bounds__(256) void f5_kernel(const unsigned short* __restrict__ tb,
                                                 const unsigned short* __restrict__ wt_b0,
                                                 const float* __restrict__ b_c2,
                                                 const int* __restrict__ starts0,
                                                 unsigned short* __restrict__ p0h,
                                                 unsigned short* __restrict__ p0l,
                                                 const unsigned short* __restrict__ t1,
                                                 const unsigned short* __restrict__ wt_b1,
                                                 const float* __restrict__ b_c4,
                                                 const int* __restrict__ starts1,
                                                 unsigned short* __restrict__ p1h,
                                                 unsigned short* __restrict__ p1l) {
    int bid = blockIdx.x;
    if (bid < 2048) {
        int b = bid;
        int g = (b & 7) | ((b >> 5) << 3);
        int cb = (b >> 3) & 3;
        conv2_pool_dev<96, 3>(cb, g, tb, wt_b0, b_c2, starts0, p0h, p0l, OC0, 1920);
    } else {
        int b = bid - 2048;   // 2048 % 8 == 0 -> b mod 8 preserved
        int g = (b & 7) | ((b >> 4) << 3);
        int cb = (b >> 3) & 1;
        conv2_pool_dev<64, 2>(cb, g, t1, wt_b1, b_c4, starts1, p1h, p1l, OC1, 896);
    }
}

// f6: gemm1(b0) [256] + gemm1(b1) [256]
__global__ __launch_bounds__(256) void f6_kernel(const unsigned short* __restrict__ p0h,
                                                 const unsigned short* __restrict__ p0l,
                                                 const unsigned short* __restrict__ bt1h0,
                                                 const unsigned short* __restrict__ bt1l0,
                                                 const float* __restrict__ g0_b1,
                                                 unsigned short* __restrict__ m1h0,
                                                 unsigned short* __restrict__ m1l0,
                                                 const unsigned short* __restrict__ p1h,
                                                 const unsigned short* __restrict__ p1l,
                                                 const unsigned short* __restrict__ bt1h1,
                                                 const unsigned short* __restrict__ bt1l1,
                                                 const float* __restrict__ g1_b1,
                                                 unsigned short* __restrict__ m1h1,
                                                 unsigned short* __restrict__ m1l1) {
    int bid = blockIdx.x;
    if (bid < 256)
        gemm3x_dev<0>(bid & 15, bid >> 4, 16, p0h, p0l, bt1h0, bt1l0, g0_b1,
                      nullptr, m1h0, m1l0, 1920);
    else {
        int b = bid - 256;
        gemm3x_dev<0>(b & 15, b >> 4, 16, p1h, p1l, bt1h1, bt1l1, g1_b1,
                      nullptr, m1h1, m1l1, 896);
    }
}

// f7: gemm2(b0) [128] + gemm2(b1) [128]
__global__ __launch_bounds__(256) void f7_kernel(const unsigned short* __restrict__ m1h0,
                                                 const unsigned short* __restrict__ m1l0,
                                                 const unsigned short* __restrict__ bt2h0,
                                                 const unsigned short* __restrict__ bt2l0,
                                                 const float* __restrict__ g0_b2,
                                                 float* __restrict__ pbn0,
                                                 const unsigned short* __restrict__ m1h1,
                                                 const unsigned short* __restrict__ m1l1,
                                                 const unsigned short* __restrict__ bt2h1,
                                                 const unsigned short* __restrict__ bt2l1,
                                                 const float* __restrict__ g1_b2,
                                                 float* __restrict__ pbn1) {
    int bid = blockIdx.x;
    if (bid < 128)
        gemm3x_dev<1>(bid & 7, bid >> 3, 8, m1h0, m1l0, bt2h0, bt2l0, g0_b2,
                      pbn0, nullptr, nullptr, 1024);
    else {
        int b = bid - 128;
        gemm3x_dev<1>(b & 7, b >> 3, 8, m1h1, m1l1, bt2h1, bt2l1, g1_b2,
                      pbn1, nullptr, nullptr, 1024);
    }
}

// f8: bn(b0) [512] + bn(b1) [512]
__global__ __launch_bounds__(256) void f8_kernel(const float* __restrict__ pbn0,
                                                 const float* __restrict__ g0_bn_g,
                                                 const float* __restrict__ g0_bn_b,
                                                 float* __restrict__ out_xg0,
                                                 unsigned short* __restrict__ xgh0,
                                                 unsigned short* __restrict__ xgl0,
                                                 const float* __restrict__ pbn1,
                                                 const float* __restrict__ g1_bn_g,
                                                 const float* __restrict__ g1_bn_b,
                                                 float* __restrict__ out_xg1,
                                                 unsigned short* __restrict__ xgh1,
                                                 unsigned short* __restrict__ xgl1) {
    int bid = blockIdx.x;
    if (bid < 512)
        bn_dev(bid, pbn0, g0_bn_g, g0_bn_b, out_xg0, xgh0, xgl0);
    else
        bn_dev(bid - 512, pbn1, g1_bn_g, g1_bn_b, out_xg1, xgh1, xgl1);
}

// f9: gemmH(b0) [64] + gemmH(b1) [64]
__global__ __launch_bounds__(256) void f9_kernel(const unsigned short* __restrict__ xgh0,
                                                 const unsigned short* __restrict__ xgl0,
                                                 const unsigned short* __restrict__ bt3h0,
                                                 const unsigned short* __restrict__ bt3l0,
                                                 const float* __restrict__ f0_b1,
                                                 float* __restrict__ hbuf0,
                                                 const unsigned short* __restrict__ xgh1,
                                                 const unsigned short* __restrict__ xgl1,
                                                 const unsigned short* __restrict__ bt3h1,
                                                 const unsigned short* __restrict__ bt3l1,
                                                 const float* __restrict__ f1_b1,
                                                 float* __restrict__ hbuf1) {
    int bid = blockIdx.x;
    if (bid < 64)
        gemm3x_dev<2>(bid & 3, bid >> 2, 4, xgh0, xgl0, bt3h0, bt3l0, f0_b1,
                      hbuf0, nullptr, nullptr, 512);
    else {
        int b = bid - 64;
        gemm3x_dev<2>(b & 3, b >> 2, 4, xgh1, xgl1, bt3h1, bt3l1, f1_b1,
                      hbuf1, nullptr, nullptr, 512);
    }
}

// f10: head2(b0) [128] + head2(b1) [128]
__global__ __launch_bounds__(256) void f10_kernel(const float* __restrict__ hbuf0,
                                                  const float* __restrict__ f0_w2,
                                                  const float* __restrict__ f0_b2,
                                                  float* __restrict__ out_z,
                                                  const float* __restrict__ hbuf1,
                                                  const float* __restrict__ f1_w2,
                                                  const float* __restrict__ f1_b2,
                                                  float* __restrict__ out_z1) {
    int bid = blockIdx.x;
    if (bid < 128)
        head2_dev(bid, hbuf0, f0_w2, f0_b2, out_z, GCONST);
    else
        head2_dev(bid - 128, hbuf1, f1_w2, f1_b2, out_z1, GCONST);
}

// ---------------------------------------------------------------------------
// launch
// ---------------------------------------------------------------------------
static inline int ceildiv(int a, int b) { return (a + b - 1) / b; }

extern "C" void kernel_launch(void* const* d_in, const int* in_sizes, int n_in,
                              void* d_out, int out_size, void* d_ws, size_t ws_size,
                              hipStream_t stream) {
    const float* x0   = (const float*)d_in[0];
    const float* x1   = (const float*)d_in[1];
    const int*   ei0  = (const int*)d_in[2];
    const int*   ei1  = (const int*)d_in[3];
    const int*   bat0 = (const int*)d_in[4];
    const int*   bat1 = (const int*)d_in[5];
    const float* w_c1 = (const float*)d_in[6];
    const float* b_c1 = (const float*)d_in[7];
    const float* w_c2 = (const float*)d_in[8];
    const float* b_c2 = (const float*)d_in[9];
    const float* w_c3 = (const float*)d_in[10];
    const float* b_c3 = (const float*)d_in[11];
    const float* w_c4 = (const float*)d_in[12];
    const float* b_c4 = (const float*)d_in[13];
    const float* g0_w1 = (const float*)d_in[14];
    const float* g0_b1 = (const float*)d_in[15];
    const float* g0_w2 = (const float*)d_in[16];
    const float* g0_b2 = (const float*)d_in[17];
    const float* g0_bn_g = (const float*)d_in[18];
    const float* g0_bn_b = (const float*)d_in[19];
    const float* g1_w1 = (const float*)d_in[20];
    const float* g1_b1 = (const float*)d_in[21];
    const float* g1_w2 = (const float*)d_in[22];
    const float* g1_b2 = (const float*)d_in[23];
    const float* g1_bn_g = (const float*)d_in[24];
    const float* g1_bn_b = (const float*)d_in[25];
    const float* f0_w1 = (const float*)d_in[26];
    const float* f0_b1 = (const float*)d_in[27];
    const float* f0_w2 = (const float*)d_in[28];
    const float* f0_b2 = (const float*)d_in[29];
    const float* f1_w1 = (const float*)d_in[30];
    const float* f1_b1 = (const float*)d_in[31];
    const float* f1_w2 = (const float*)d_in[32];
    const float* f1_b2 = (const float*)d_in[33];

    float* out = (float*)d_out;
    float* out_z   = out;
    float* out_xg0 = out + 1024;
    float* out_xg1 = out + 1024 + 262144;
    float* out_z1  = out + 1024 + 262144 + 262144;

    // workspace carve (floats; all offsets multiples of 4 -> 16B aligned)
    float* ws = (float*)d_ws;
    size_t off = 0;
    auto alloc = [&](size_t n) { float* p = ws + off; off += n; return p; };
    unsigned short* xb0 = (unsigned short*)alloc((size_t)N0 * 96 / 2); // x0 bf16; later t1 (b1 feat buf)
    unsigned short* xb1 = (unsigned short*)alloc((size_t)N1 * 64 / 2); // x1 bf16; later y1 (b1 conv1 out)
    unsigned short* tb  = (unsigned short*)alloc((size_t)N0 * 96 / 2); // staging0 overlay; b0 gather out
    unsigned short* yb  = (unsigned short*)alloc((size_t)N0 * 96 / 2); // staging1 overlay; b0 conv1 out
    unsigned short* wt_a0 = (unsigned short*)alloc(96 * 96 / 2);
    unsigned short* wt_b0 = (unsigned short*)alloc(1024 * 96 / 2);
    unsigned short* wt_a1 = (unsigned short*)alloc(48 * 64 / 2);
    unsigned short* wt_b1 = (unsigned short*)alloc(512 * 64 / 2);
    // MLP hi/lo weights, per branch
    unsigned short* bt1h0 = (unsigned short*)alloc((size_t)1024 * 1920 / 2);
    unsigned short* bt1l0 = (unsigned short*)alloc((size_t)1024 * 1920 / 2);
    unsigned short* bt2h0 = (unsigned short*)alloc((size_t)512 * 1024 / 2);
    unsigned short* bt2l0 = (unsigned short*)alloc((size_t)512 * 1024 / 2);
    unsigned short* bt3h0 = (unsigned short*)alloc((size_t)256 * 512 / 2);
    unsigned short* bt3l0 = (unsigned short*)alloc((size_t)256 * 512 / 2);
    unsigned short* bt1h1 = (unsigned short*)alloc((size_t)1024 * 896 / 2);
    unsigned short* bt1l1 = (unsigned short*)alloc((size_t)1024 * 896 / 2);
    unsigned short* bt2h1 = (unsigned short*)alloc((size_t)512 * 1024 / 2);
    unsigned short* bt2l1 = (unsigned short*)alloc((size_t)512 * 1024 / 2);
    unsigned short* bt3h1 = (unsigned short*)alloc((size_t)256 * 512 / 2);
    unsigned short* bt3l1 = (unsigned short*)alloc((size_t)256 * 512 / 2);
    // activations, per branch
    unsigned short* m1h0 = (unsigned short*)alloc((size_t)512 * 1024 / 2);
    unsigned short* m1l0 = (unsigned short*)alloc((size_t)512 * 1024 / 2);
    unsigned short* m1h1 = (unsigned short*)alloc((size_t)512 * 1024 / 2);
    unsigned short* m1l1 = (unsigned short*)alloc((size_t)512 * 1024 / 2);
    unsigned short* xgh0 = (unsigned short*)alloc((size_t)512 * 512 / 2);
    unsigned short* xgl0 = (unsigned short*)alloc((size_t)512 * 512 / 2);
    unsigned short* xgh1 = (unsigned short*)alloc((size_t)512 * 512 / 2);
    unsigned short* xgl1 = (unsigned short*)alloc((size_t)512 * 512 / 2);
    unsigned short* p0h = (unsigned short*)alloc((size_t)512 * 1920 / 2);
    unsigned short* p0l = (unsigned short*)alloc((size_t)512 * 1920 / 2);
    unsigned short* p1h = (unsigned short*)alloc((size_t)512 * 896 / 2);
    unsigned short* p1l = (unsigned short*)alloc((size_t)512 * 896 / 2);
    float* pbn0  = alloc((size_t)512 * 512);
    float* pbn1  = alloc((size_t)512 * 512);
    float* hbuf0 = alloc((size_t)512 * 256);
    float* hbuf1 = alloc((size_t)512 * 256);
    // CSR
    int* bbase2 = (int*)alloc(1024);
    int* bcur2  = (int*)alloc(1024);
    int* rowptr0 = (int*)alloc(100016);
    int* col0    = (int*)alloc(E0C);
    int* rowptr1 = (int*)alloc(100016);
    int* col1    = (int*)alloc(E1C);
    int* starts0 = (int*)alloc(520);
    int* starts1 = (int*)alloc(520);
    // staging slab overlays (NBKT*SLAB int2 = 18.8MB <= 19.2MB tb/yb regions;
    // dead after f0; tb/yb first written in f1/f2)
    int2* staging0 = (int2*)tb;
    int2* staging1 = (int2*)yb;
    // branch1 overlays (xb0/xb1 dead after their last reads in f1/f2)
    unsigned short* t1 = xb0;
    unsigned short* y1 = xb1;

    // ------------------------------ prologue ------------------------------
    misc_kernel<<<7, 256, 0, stream>>>(bat0, bat1, starts0, starts1, bcur2);
    edge_bucket2_kernel<<<3804, 256, 0, stream>>>(ei0, ei1, E0C, bcur2,
                                                  staging0, staging1,
                                                  w_c1, w_c2, w_c3, w_c4,
                                                  wt_a0, wt_b0, wt_a1, wt_b1,
                                                  p0h, p0l, p1h, p1l);
    bucket_scan2_kernel<<<2, 512, 0, stream>>>(bcur2, bbase2);
    f0_kernel<<<2 * NBKT + 50000 + 25000, 256, 0, stream>>>(
        staging0, staging1, bcur2, bbase2, rowptr0, rowptr1, col0, col1,
        xb0, x0, xb1, x1);

    // ------------------- pipelined cross-branch schedule -------------------
    f1_kernel<<<75000 + 4096, 256, 0, stream>>>(
        tb, xb0, rowptr0, col0,
        g0_w1, g0_w2, f0_w1, g1_w1, g1_w2, f1_w1,
        bt1h0, bt1l0, bt2h0, bt2l0, bt3h0, bt3l0,
        bt1h1, bt1l1, bt2h1, bt2l1, bt3h1, bt3l1);
    f2_kernel<<<50000 + 1563, 256, 0, stream>>>(t1, xb1, rowptr1, col1,
                                                tb, wt_a0, b_c1, yb);
    f3_kernel<<<75000 + 1563, 256, 0, stream>>>(tb, yb, rowptr0, col0,
                                                t1, wt_a1, b_c3, y1);
    f4_kernel<<<50000, 256, 0, stream>>>(t1, y1, rowptr1, col1);
    f5_kernel<<<2048 + 1024, 256, 0, stream>>>(tb, wt_b0, b_c2, starts0, p0h, p0l,
                                               t1, wt_b1, b_c4, starts1, p1h, p1l);
    f6_kernel<<<256 + 256, 256, 0, stream>>>(p0h, p0l, bt1h0, bt1l0, g0_b1, m1h0, m1l0,
                                             p1h, p1l, bt1h1, bt1l1, g1_b1, m1h1, m1l1);
    f7_kernel<<<128 + 128, 256, 0, stream>>>(m1h0, m1l0, bt2h0, bt2l0, g0_b2, pbn0,
                                             m1h1, m1l1, bt2h1, bt2l1, g1_b2, pbn1);
    f8_kernel<<<512 + 512, 256, 0, stream>>>(pbn0, g0_bn_g, g0_bn_b, out_xg0, xgh0, xgl0,
                                             pbn1, g1_bn_g, g1_bn_b, out_xg1, xgh1, xgl1);
    f9_kernel<<<64 + 64, 256, 0, stream>>>(xgh0, xgl0, bt3h0, bt3l0, f0_b1, hbuf0,
                                           xgh1, xgl1, bt3h1, bt3l1, f1_b1, hbuf1);
    f10_kernel<<<128 + 128, 256, 0, stream>>>(hbuf0, f0_w2, f0_b2, out_z,
                                              hbuf1, f1_w2, f1_b2, out_z1);
}

// Round 8
// 654.368 us; speedup vs baseline: 1.2328x; 1.2328x over previous
//
#include <hip/hip_runtime.h>
#include <hip/hip_bf16.h>

// ---------------------------------------------------------------------------
// Problem constants
// ---------------------------------------------------------------------------
#define N0 100000
#define E0C 1600000
#define N1 100000
#define E1C 1600000
#define GCONST 512
#define F0C 93
#define F1C 43
#define OC0 (F0C * 10)   // 930
#define OC1 (F1C * 10)   // 430
#define BN_EPS 1e-5f
#define NBKT 391         // ceil(100000 / 256) buckets for CSR fill
#define SLAB 6016        // staging slab per bucket (avg 4092, sigma~64 -> +30 sigma)

typedef __attribute__((ext_vector_type(8))) short short8;
typedef __attribute__((ext_vector_type(4))) float floatx4;

static __device__ __forceinline__ unsigned short f2bf(float f) {
    unsigned u = __float_as_uint(f);
    unsigned r = (u + 0x7FFF + ((u >> 16) & 1)) >> 16;   // RNE
    return (unsigned short)r;
}
static __device__ __forceinline__ float bf2f(unsigned short u) {
    return __uint_as_float(((unsigned)u) << 16);
}
static __device__ __forceinline__ void split_bf(float v, unsigned short& h, unsigned short& l) {
    h = f2bf(v);
    l = f2bf(v - bf2f(h));
}

// ---------------------------------------------------------------------------
// misc: find_starts [0,6) + slab cursor init [6] + bnsum zero [7]
// ---------------------------------------------------------------------------
__global__ __launch_bounds__(256) void misc_kernel(const int* __restrict__ bat0,
                                                   const int* __restrict__ bat1,
                                                   int* __restrict__ st0,
                                                   int* __restrict__ st1,
                                                   int* __restrict__ bcur2,
                                                   float* __restrict__ bnsum0,
                                                   float* __restrict__ bnsum1) {
    int bid = blockIdx.x;
    int t = threadIdx.x;
    if (bid < 6) {
        int branch = bid / 3;
        const int* batch = branch ? bat1 : bat0;
        int* starts = branch ? st1 : st0;
        int g = (bid % 3) * 256 + t;
        if (g > GCONST) return;
        if (g == GCONST) { starts[GCONST] = N0; return; }
        int lo = 0, hi = N0;
        while (lo < hi) {
            int mid = (lo + hi) >> 1;
            if (batch[mid] < g) lo = mid + 1; else hi = mid;
        }
        starts[g] = lo;
    } else if (bid == 6) {
        for (int i = t; i < 1024; i += 256) {
            if (i < NBKT) bcur2[i] = i * SLAB;
            else if (i >= 512 && i < 512 + NBKT) bcur2[i] = (i - 512) * SLAB;
        }
    } else {
        for (int i = t; i < 1024; i += 256) {
            bnsum0[i] = 0.f;
            bnsum1[i] = 0.f;
        }
    }
}

// ---------------------------------------------------------------------------
// edge_bucket2: edges(b0) [0,782) | edges(b1) [782,1564) | wt_prep [1564,3612)
//               | p0 pad [3612,3732) | p1 pad [3732,3804)
// ---------------------------------------------------------------------------
__global__ __launch_bounds__(256) void edge_bucket2_kernel(const int* __restrict__ ei0,
                                                           const int* __restrict__ ei1,
                                                           int E, int* __restrict__ bcur2,
                                                           int2* __restrict__ st0,
                                                           int2* __restrict__ st1,
                                                           const float* __restrict__ Wc1,
                                                           const float* __restrict__ Wc2,
                                                           const float* __restrict__ Wc3,
                                                           const float* __restrict__ Wc4,
                                                           unsigned short* __restrict__ Ta0,
                                                           unsigned short* __restrict__ Tb0,
                                                           unsigned short* __restrict__ Ta1,
                                                           unsigned short* __restrict__ Tb1,
                                                           unsigned short* __restrict__ p0h,
                                                           unsigned short* __restrict__ p0l,
                                                           unsigned short* __restrict__ p1h,
                                                           unsigned short* __restrict__ p1l) {
    int bid = blockIdx.x;
    int t = threadIdx.x;
    if (bid < 1564) {
        int branch = bid >= 782;
        int blk = branch ? bid - 782 : bid;
        const int* ei = branch ? ei1 : ei0;
        int* bcur = bcur2 + branch * 512;
        int2* staging = branch ? st1 : st0;
        __shared__ int hist[NBKT];
        __shared__ int gbase[NBKT];
        for (int i = t; i < NBKT; i += 256) hist[i] = 0;
        __syncthreads();
        int base = blk * 2048;
        int srcv[8], dstv[8];
#pragma unroll
        for (int i = 0; i < 8; ++i) {
            int e = base + i * 256 + t;
            if (e < E) { srcv[i] = ei[e]; dstv[i] = ei[E + e]; }
            else dstv[i] = -1;
        }
#pragma unroll
        for (int i = 0; i < 8; ++i)
            if (dstv[i] >= 0) atomicAdd(&hist[dstv[i] >> 8], 1);
        __syncthreads();
        for (int i = t; i < NBKT; i += 256) {
            int c = hist[i];
            gbase[i] = c ? atomicAdd(&bcur[i], c) : 0;
            hist[i] = 0;   // reuse as local cursor
        }
        __syncthreads();
#pragma unroll
        for (int i = 0; i < 8; ++i) {
            if (dstv[i] >= 0) {
                int b = dstv[i] >> 8;
                int lofs = atomicAdd(&hist[b], 1);
                staging[gbase[b] + lofs] = make_int2(srcv[i], dstv[i]);
            }
        }
    } else if (bid < 3612) {
        int idx = bid - 1564;
        int cfg = idx >> 9;
        int c = (idx & 511) * 2 + (t >> 7);
        int k = t & 127;
        const float* W; unsigned short* T; int OCr, Fr, KP, RB;
        switch (cfg) {
            case 0:  W = Wc1; T = Ta0; OCr = 93;  Fr = 93; KP = 96; RB = 96;   break;
            case 1:  W = Wc2; T = Tb0; OCr = 930; Fr = 93; KP = 96; RB = 1024; break;
            case 2:  W = Wc3; T = Ta1; OCr = 43;  Fr = 43; KP = 64; RB = 48;   break;
            default: W = Wc4; T = Tb1; OCr = 430; Fr = 43; KP = 64; RB = 512;  break;
        }
        if (c >= RB || k >= KP) return;
        unsigned short v = 0;
        if (c < OCr && k < Fr) v = f2bf(W[(size_t)k * OCr + c]);
        T[(size_t)c * KP + k] = v;
    } else if (bid < 3732) {
        int i = (bid - 3612) * 256 + t;
        if (i >= GCONST * 60) return;
        int g = i / 60, c = 1860 + (i - g * 60);
        p0h[(size_t)g * 1920 + c] = 0;
        p0l[(size_t)g * 1920 + c] = 0;
    } else {
        int i = (bid - 3732) * 256 + t;
        if (i >= GCONST * 36) return;
        int g = i / 36, c = 860 + (i - g * 36);
        p1h[(size_t)g * 896 + c] = 0;
        p1l[(size_t)g * 896 + c] = 0;
    }
}

// ---------------------------------------------------------------------------
// bucket_scan2: recover bucket counts from slab cursors, exclusive scan
// ---------------------------------------------------------------------------
__global__ __launch_bounds__(512) void bucket_scan2_kernel(const int* __restrict__ bcur2,
                                                           int* __restrict__ bbase2) {
    const int* bcur = bcur2 + blockIdx.x * 512;
    int* bbase = bbase2 + blockIdx.x * 512;
    __shared__ int sh[512];
    int t = threadIdx.x;
    int cnt = (t < NBKT) ? bcur[t] - t * SLAB : 0;
    sh[t] = cnt;
    __syncthreads();
    for (int o = 1; o < 512; o <<= 1) {
        int add = (t >= o) ? sh[t - o] : 0;
        __syncthreads();
        sh[t] += add;
        __syncthreads();
    }
    if (t <= NBKT) bbase[t] = sh[t] - cnt;   // exclusive; t==NBKT -> total==E
}

// per-bucket fused {LDS histogram -> scan -> rowptr -> col scatter} from slab
static __device__ __forceinline__ void csr_build_dev(int b, const int2* __restrict__ staging,
                                                     const int* __restrict__ bcur,
                                                     const int* __restrict__ bbase, int N,
                                                     int* __restrict__ rowptr,
                                                     int* __restrict__ col) {
    __shared__ int h[256];
    __shared__ int sc[256];
    int t = threadIdx.x;
    int sl = b * SLAB;
    int se = bcur[b];
    int go = bbase[b];
    h[t] = 0;
    __syncthreads();
    for (int i = sl + t; i < se; i += 256)
        atomicAdd(&h[staging[i].y & 255], 1);
    __syncthreads();
    int v = h[t];
    sc[t] = v;
    __syncthreads();
    for (int o = 1; o < 256; o <<= 1) {
        int add = (t >= o) ? sc[t - o] : 0;
        __syncthreads();
        sc[t] += add;
        __syncthreads();
    }
    int ex = go + (sc[t] - v);
    int node = (b << 8) + t;
    if (node <= N) rowptr[node] = ex;
    __syncthreads();
    sc[t] = ex;                          // reuse as cursor
    __syncthreads();
    for (int i = sl + t; i < se; i += 256) {
        int2 ed = staging[i];
        int pos = atomicAdd(&sc[ed.y & 255], 1);
        col[pos] = ed.x;
    }
}

// ---------------------------------------------------------------------------
// MLP weight transpose + hi/lo bf16 split (device body; fused into f1)
// ---------------------------------------------------------------------------
static __device__ __forceinline__ void wsplit_dev(int k0, int c0,
                                                  const float* __restrict__ W,
                                                  unsigned short* __restrict__ Th,
                                                  unsigned short* __restrict__ Tl,
                                                  int K, int N, int KP) {
    __shared__ float tile[32][33];
    int tx = threadIdx.x & 31, ty = threadIdx.x >> 5;
    for (int r = ty; r < 32; r += 8) {
        int k = k0 + r;
        tile[r][tx] = (k < K) ? W[(size_t)k * N + c0 + tx] : 0.f;
    }
    __syncthreads();
    for (int r = ty; r < 32; r += 8) {
        int c = c0 + r;
        float v = tile[tx][r];
        unsigned short h, l;
        split_bf(v, h, l);
        Th[(size_t)c * KP + k0 + tx] = h;
        Tl[(size_t)c * KP + k0 + tx] = l;
    }
}

// ---------------------------------------------------------------------------
// gather-aggregate: one wave per node, 16B vector loads, 2 rows in flight.
// (round-6 form; chunked variant regressed: +80MB index traffic, no L2 win)
// ---------------------------------------------------------------------------
template<int KP, int CH, int GR>
static __device__ __forceinline__ void gather_dev(int nb, unsigned short* __restrict__ t,
                                                  const unsigned short* __restrict__ x,
                                                  const int* __restrict__ rowptr,
                                                  const int* __restrict__ col, int N) {
    int wave = threadIdx.x >> 6, lane = threadIdx.x & 63;
    int node = nb * 4 + wave;
    if (node >= N) return;
    int g = lane / CH;
    int c = lane - g * CH;
    bool act = (g < GR);
    int s = rowptr[node], e = rowptr[node + 1];
    float acc[8] = {0.f, 0.f, 0.f, 0.f, 0.f, 0.f, 0.f, 0.f};
    int j = act ? (s - 1 + g) : e;
    int src0 = node;
    if (j >= s && j < e) src0 = col[j];
    while (j < e) {
        int jb = j + GR;
        int jc = jb + GR;
        int srcb = (jb < e) ? col[jb] : 0;
        int srcc = (jc < e) ? col[jc] : 0;
        short8 v0 = *(const short8*)(x + (size_t)src0 * KP + c * 8);
#pragma unroll
        for (int i = 0; i < 8; ++i) acc[i] += bf2f((unsigned short)v0[i]);
        if (jb < e) {
            short8 v1 = *(const short8*)(x + (size_t)srcb * KP + c * 8);
#pragma unroll
            for (int i = 0; i < 8; ++i) acc[i] += bf2f((unsigned short)v1[i]);
        }
        j = jc; src0 = srcc;
    }
    if (GR == 8) {
#pragma unroll
        for (int i = 0; i < 8; ++i) {
            float v = acc[i];
            v += __shfl_xor(v, 8);
            v += __shfl_xor(v, 16);
            v += __shfl_xor(v, 32);
            acc[i] = v;
        }
    } else {
#pragma unroll
        for (int i = 0; i < 8; ++i) {
            float v = acc[i];
            float v1 = __shfl(v, lane + CH);
            float v2 = __shfl(v, lane + 2 * CH);
            float v3 = __shfl(v, lane + 3 * CH);
            float v4 = __shfl(v, lane + 4 * CH);
            acc[i] = v + v1 + v2 + v3 + v4;
        }
    }
    if (lane < CH) {
        short8 o;
#pragma unroll
        for (int i = 0; i < 8; ++i) o[i] = (short)f2bf(acc[i]);
        *(short8*)(t + (size_t)node * KP + lane * 8) = o;
    }
}

// conv1 via MFMA: y = relu(t @ W + b), bf16 [N][KP]
template<int KP, int KS, int NT>
static __device__ __forceinline__ void conv1_dev(int nb, const unsigned short* __restrict__ t,
                                                 const unsigned short* __restrict__ Wt,
                                                 const float* __restrict__ bias,
                                                 unsigned short* __restrict__ y,
                                                 int NC, int N) {
    int wave = threadIdx.x >> 6, lane = threadIdx.x & 63;
    int quad = lane >> 4, l15 = lane & 15;
    int r0 = (nb * 4 + wave) * 16;
    const short8 z8 = {0, 0, 0, 0, 0, 0, 0, 0};
    short8 a[KS];
    int arow = r0 + l15;
#pragma unroll
    for (int ks = 0; ks < KS; ++ks)
        a[ks] = (arow < N) ? *(const short8*)(t + (size_t)arow * KP + ks * 32 + quad * 8) : z8;
#pragma unroll
    for (int nt = 0; nt < NT; ++nt) {
        int colb = nt * 16 + l15;
        floatx4 c = {0.f, 0.f, 0.f, 0.f};
#pragma unroll
        for (int ks = 0; ks < KS; ++ks) {
            short8 b = *(const short8*)(Wt + (size_t)colb * KP + ks * 32 + quad * 8);
            c = __builtin_amdgcn_mfma_f32_16x16x32_bf16(a[ks], b, c, 0, 0, 0);
        }
        float bc = (colb < NC) ? bias[colb] : 0.f;
#pragma unroll
        for (int r = 0; r < 4; ++r) {
            int row = r0 + quad * 4 + r;
            if (row < N) {
                float o = fmaxf(c[r] + bc, 0.f);
                y[(size_t)row * KP + colb] = f2bf(o);
            }
        }
    }
}

// conv2 + relu + mean/max pool, epilogue emits hi/lo bf16 pooled rows
template<int KP, int KS>
static __device__ __forceinline__ void conv2_pool_dev(int cb, int g,
                                                      const unsigned short* __restrict__ t,
                                                      const unsigned short* __restrict__ Wt,
                                                      const float* __restrict__ bias,
                                                      const int* __restrict__ starts,
                                                      unsigned short* __restrict__ ph,
                                                      unsigned short* __restrict__ pl,
                                                      int OC, int KPad) {
    int wave = threadIdx.x >> 6, lane = threadIdx.x & 63;
    int quad = lane >> 4, l15 = lane & 15;
    int cw0 = cb * 256 + wave * 64;
    short8 bfr[4][KS];
    float bs[4];
#pragma unroll
    for (int ti = 0; ti < 4; ++ti) {
        int colb = cw0 + ti * 16 + l15;
#pragma unroll
        for (int ks = 0; ks < KS; ++ks)
            bfr[ti][ks] = *(const short8*)(Wt + (size_t)colb * KP + ks * 32 + quad * 8);
        bs[ti] = (colb < OC) ? bias[colb] : 0.f;
    }
    int s = starts[g], e = starts[g + 1];
    float sum[4] = {0.f, 0.f, 0.f, 0.f};
    float mx[4]  = {0.f, 0.f, 0.f, 0.f};
    const short8 z8 = {0, 0, 0, 0, 0, 0, 0, 0};
    for (int ns = s; ns < e; ns += 16) {
        short8 a[KS];
        int arow = ns + l15;
        bool av = arow < e;
#pragma unroll
        for (int ks = 0; ks < KS; ++ks)
            a[ks] = av ? *(const short8*)(t + (size_t)arow * KP + ks * 32 + quad * 8) : z8;
        int rbase = ns + quad * 4;
#pragma unroll
        for (int ti = 0; ti < 4; ++ti) {
            floatx4 c = {0.f, 0.f, 0.f, 0.f};
#pragma unroll
            for (int ks = 0; ks < KS; ++ks)
                c = __builtin_amdgcn_mfma_f32_16x16x32_bf16(a[ks], bfr[ti][ks], c, 0, 0, 0);
#pragma unroll
            for (int r = 0; r < 4; ++r) {
                float o = fmaxf(c[r] + bs[ti], 0.f);
                if (rbase + r < e) {
                    sum[ti] += o;
                    mx[ti] = fmaxf(mx[ti], o);
                }
            }
        }
    }
    int cnt = e - s;
    float rc = 1.f / (float)(cnt > 0 ? cnt : 1);
#pragma unroll
    for (int ti = 0; ti < 4; ++ti) {
        float sv = sum[ti], mv = mx[ti];
        sv += __shfl_down(sv, 32);
        mv = fmaxf(mv, __shfl_down(mv, 32));
        sv += __shfl_down(sv, 16);
        mv = fmaxf(mv, __shfl_down(mv, 16));
        if (lane < 16) {
            int colb = cw0 + ti * 16 + l15;
            if (colb < OC) {
                size_t base = (size_t)g * (size_t)KPad;
                unsigned short h, l;
                split_bf(sv * rc, h, l);
                ph[base + colb] = h; pl[base + colb] = l;
                split_bf(mv, h, l);
                ph[base + OC + colb] = h; pl[base + OC + colb] = l;
            }
        }
    }
}

// split-bf16 ("bf16x3") MFMA GEMM tile: C = A @ B^T(+bias), fp32-equivalent.
// MODE 0: relu, write hi/lo bf16.  MODE 1: fp32.  MODE 2: relu, fp32.
// MODE 3: fp32 + fused BN-stat accumulation (block LDS reduce -> 64 global
//         atomics into bnsum[col]=sum, bnsum[512+col]=sumsq).
template<int MODE>
static __device__ __forceinline__ void gemm3x_dev(int bx, int by, int NBX,
                                                  const unsigned short* __restrict__ Ah,
                                                  const unsigned short* __restrict__ Al,
                                                  const unsigned short* __restrict__ Bh,
                                                  const unsigned short* __restrict__ Bl,
                                                  const float* __restrict__ bias,
                                                  float* __restrict__ Cf,
                                                  unsigned short* __restrict__ Ch,
                                                  unsigned short* __restrict__ Cl,
                                                  int KP,
                                                  float* __restrict__ bnsum = nullptr) {
    int wave = threadIdx.x >> 6, lane = threadIdx.x & 63;
    int quad = lane >> 4, l15 = lane & 15;
    int r0 = by * 32 + (wave & 1) * 16;
    int c0 = bx * 64 + (wave >> 1) * 32;
    int Ncols = NBX * 64;
    floatx4 acc0 = {0.f, 0.f, 0.f, 0.f};
    floatx4 acc1 = {0.f, 0.f, 0.f, 0.f};
    const unsigned short* arh = Ah + (size_t)(r0 + l15) * KP;
    const unsigned short* arl = Al + (size_t)(r0 + l15) * KP;
    const unsigned short* b0h = Bh + (size_t)(c0 + l15) * KP;
    const unsigned short* b0l = Bl + (size_t)(c0 + l15) * KP;
    const unsigned short* b1h = Bh + (size_t)(c0 + 16 + l15) * KP;
    const unsigned short* b1l = Bl + (size_t)(c0 + 16 + l15) * KP;
    for (int k0 = 0; k0 < KP; k0 += 128) {
        short8 ah[4], al[4];
#pragma unroll
        for (int q = 0; q < 4; ++q) {
            ah[q] = *(const short8*)(arh + k0 + q * 32 + quad * 8);
            al[q] = *(const short8*)(arl + k0 + q * 32 + quad * 8);
        }
#pragma unroll
        for (int q = 0; q < 4; ++q) {
            short8 bh = *(const short8*)(b0h + k0 + q * 32 + quad * 8);
            short8 bl = *(const short8*)(b0l + k0 + q * 32 + quad * 8);
            acc0 = __builtin_amdgcn_mfma_f32_16x16x32_bf16(ah[q], bh, acc0, 0, 0, 0);
            acc0 = __builtin_amdgcn_mfma_f32_16x16x32_bf16(al[q], bh, acc0, 0, 0, 0);
            acc0 = __builtin_amdgcn_mfma_f32_16x16x32_bf16(ah[q], bl, acc0, 0, 0, 0);
            bh = *(const short8*)(b1h + k0 + q * 32 + quad * 8);
            bl = *(const short8*)(b1l + k0 + q * 32 + quad * 8);
            acc1 = __builtin_amdgcn_mfma_f32_16x16x32_bf16(ah[q], bh, acc1, 0, 0, 0);
            acc1 = __builtin_amdgcn_mfma_f32_16x16x32_bf16(al[q], bh, acc1, 0, 0, 0);
            acc1 = __builtin_amdgcn_mfma_f32_16x16x32_bf16(ah[q], bl, acc1, 0, 0, 0);
        }
    }
    int col0 = c0 + l15, col1 = c0 + 16 + l15;
    float bc0 = bias[col0], bc1 = bias[col1];
    if (MODE == 3) {
        __shared__ float lsum[64], lsum2[64];
        if (threadIdx.x < 64) { lsum[threadIdx.x] = 0.f; lsum2[threadIdx.x] = 0.f; }
        __syncthreads();
        float p0 = 0.f, p0q = 0.f, p1 = 0.f, p1q = 0.f;
#pragma unroll
        for (int r = 0; r < 4; ++r) {
            int row = r0 + quad * 4 + r;
            float v0 = acc0[r] + bc0;
            float v1 = acc1[r] + bc1;
            Cf[(size_t)row * Ncols + col0] = v0;
            Cf[(size_t)row * Ncols + col1] = v1;
            p0 += v0; p0q += v0 * v0;
            p1 += v1; p1q += v1 * v1;
        }
        int cl0 = (wave >> 1) * 32 + l15;
        atomicAdd(&lsum[cl0], p0);       atomicAdd(&lsum2[cl0], p0q);
        atomicAdd(&lsum[cl0 + 16], p1);  atomicAdd(&lsum2[cl0 + 16], p1q);
        __syncthreads();
        if (threadIdx.x < 64) {
            atomicAdd(&bnsum[bx * 64 + threadIdx.x], lsum[threadIdx.x]);
            atomicAdd(&bnsum[512 + bx * 64 + threadIdx.x], lsum2[threadIdx.x]);
        }
        return;
    }
#pragma unroll
    for (int r = 0; r < 4; ++r) {
        int row = r0 + quad * 4 + r;
        float v0 = acc0[r] + bc0;
        float v1 = acc1[r] + bc1;
        if (MODE == 0 || MODE == 2) { v0 = fmaxf(v0, 0.f); v1 = fmaxf(v1, 0.f); }
        if (MODE == 0) {
            unsigned short h, l;
            split_bf(v0, h, l);
            Ch[(size_t)row * Ncols + col0] = h; Cl[(size_t)row * Ncols + col0] = l;
            split_bf(v1, h, l);
            Ch[(size_t)row * Ncols + col1] = h; Cl[(size_t)row * Ncols + col1] = l;
        } else {
            Cf[(size_t)row * Ncols + col0] = v0;
            Cf[(size_t)row * Ncols + col1] = v1;
        }
    }
}

// head2: z[row][0..1] = h[row][0..255] @ w2[256][2] + b2. Wave per row.
static __device__ __forceinline__ void head2_dev(int nb, const float* __restrict__ h,
                                                 const float* __restrict__ w2,
                                                 const float* __restrict__ b2,
                                                 float* __restrict__ z, int M) {
    int wave = threadIdx.x >> 6, lane = threadIdx.x & 63;
    int row = nb * 4 + wave;
    if (row >= M) return;
    float4 hv = *(const float4*)(h + (size_t)row * 256 + lane * 4);
    const float* wp = w2 + lane * 8;
    float s0 = hv.x * wp[0] + hv.y * wp[2] + hv.z * wp[4] + hv.w * wp[6];
    float s1 = hv.x * wp[1] + hv.y * wp[3] + hv.z * wp[5] + hv.w * wp[7];
#pragma unroll
    for (int offd = 32; offd >= 1; offd >>= 1) {
        s0 += __shfl_down(s0, offd);
        s1 += __shfl_down(s1, offd);
    }
    if (lane == 0) {
        z[(size_t)row * 2 + 0] = s0 + b2[0];
        z[(size_t)row * 2 + 1] = s1 + b2[1];
    }
}

// ---------------------------------------------------------------------------
// fused stage kernels
// ---------------------------------------------------------------------------

// f0: csr_build(both) + tobf16(both)
__global__ __launch_bounds__(256) void f0_kernel(const int2* __restrict__ st0,
                                                 const int2* __restrict__ st1,
                                                 const int* __restrict__ bcur2,
                                                 const int* __restrict__ bbase2,
                                                 int* __restrict__ rp0, int* __restrict__ rp1,
                                                 int* __restrict__ c0, int* __restrict__ c1,
                                                 unsigned short* __restrict__ xb0,
                                                 const float* __restrict__ x0,
                                                 unsigned short* __restrict__ xb1,
                                                 const float* __restrict__ x1) {
    int bid = blockIdx.x;
    if (bid < 2 * NBKT) {
        int branch = bid >= NBKT;
        csr_build_dev(branch ? bid - NBKT : bid,
                      branch ? st1 : st0,
                      bcur2 + branch * 512, bbase2 + branch * 512, N0,
                      branch ? rp1 : rp0, branch ? c1 : c0);
    } else if (bid < 2 * NBKT + 50000) {
        int b = bid - 2 * NBKT;
        int node = b * 2 + (threadIdx.x >> 7);
        int f = threadIdx.x & 127;
        if (node < N0 && f < 96)
            xb0[(size_t)node * 96 + f] = (f < 93) ? f2bf(x0[(size_t)node * 93 + f]) : (unsigned short)0;
    } else {
        int b = bid - 2 * NBKT - 50000;
        int node = b * 4 + (threadIdx.x >> 6);
        int f = threadIdx.x & 63;
        if (node < N1)
            xb1[(size_t)node * 64 + f] = (f < 43) ? f2bf(x1[(size_t)node * 43 + f]) : (unsigned short)0;
    }
}

// f1: gather-x(b0) [25000] + wsplit of all 6 MLP weights [4096]
__global__ __launch_bounds__(256) void f1_kernel(unsigned short* __restrict__ tb,
                                                 const unsigned short* __restrict__ xb0,
                                                 const int* __restrict__ rowptr0,
                                                 const int* __restrict__ col0,
                                                 const float* g0_w1, const float* g0_w2,
                                                 const float* f0_w1,
                                                 const float* g1_w1, const float* g1_w2,
                                                 const float* f1_w1,
                                                 unsigned short* bt1h0, unsigned short* bt1l0,
                                                 unsigned short* bt2h0, unsigned short* bt2l0,
                                                 unsigned short* bt3h0, unsigned short* bt3l0,
                                                 unsigned short* bt1h1, unsigned short* bt1l1,
                                                 unsigned short* bt2h1, unsigned short* bt2l1,
                                                 unsigned short* bt3h1, unsigned short* bt3l1) {
    int bid = blockIdx.x;
    if (bid < 25000) {
        gather_dev<96, 12, 5>(bid, tb, xb0, rowptr0, col0, N0);
        return;
    }
    int w = bid - 25000;
    if (w < 1920)      wsplit_dev((w % 60) * 32, (w / 60) * 32, g0_w1, bt1h0, bt1l0, 1860, 1024, 1920);
    else if (w < 2432) { w -= 1920; wsplit_dev((w % 32) * 32, (w / 32) * 32, g0_w2, bt2h0, bt2l0, 1024, 512, 1024); }
    else if (w < 2560) { w -= 2432; wsplit_dev((w % 16) * 32, (w / 16) * 32, f0_w1, bt3h0, bt3l0, 512, 256, 512); }
    else if (w < 3456) { w -= 2560; wsplit_dev((w % 28) * 32, (w / 28) * 32, g1_w1, bt1h1, bt1l1, 860, 1024, 896); }
    else if (w < 3968) { w -= 3456; wsplit_dev((w % 32) * 32, (w / 32) * 32, g1_w2, bt2h1, bt2l1, 1024, 512, 1024); }
    else               { w -= 3968; wsplit_dev((w % 16) * 32, (w / 16) * 32, f1_w1, bt3h1, bt3l1, 512, 256, 512); }
}

// f2: gather-x(b1) [25000 first] + conv1(b0) [1563]
__global__ __launch_bounds__(256) void f2_kernel(unsigned short* __restrict__ t1,
                                                 const unsigned short* __restrict__ xb1,
                                                 const int* __restrict__ rowptr1,
                                                 const int* __restrict__ col1,
                                                 const unsigned short* __restrict__ tb,
                                                 const unsigned short* __restrict__ wt_a0,
                                                 const float* __restrict__ b_c1,
                                                 unsigned short* __restrict__ yb) {
    int bid = blockIdx.x;
    if (bid < 25000)
        gather_dev<64, 8, 8>(bid, t1, xb1, rowptr1, col1, N1);
    else
        conv1_dev<96, 3, 6>(bid - 25000, tb, wt_a0, b_c1, yb, 93, N0);
}

// f3: gather-y(b0) [25000 first] + conv1(b1) [1563]
__global__ __launch_bounds__(256) void f3_kernel(unsigned short* __restrict__ tb,
                                                 const unsigned short* __restrict__ yb,
                                                 const int* __restrict__ rowptr0,
                                                 const int* __restrict__ col0,
                                                 const unsigned short* __restrict__ t1,
                                                 const unsigned short* __restrict__ wt_a1,
                                                 const float* __restrict__ b_c3,
                                                 unsigned short* __restrict__ y1) {
    int bid = blockIdx.x;
    if (bid < 25000)
        gather_dev<96, 12, 5>(bid, tb, yb, rowptr0, col0, N0);
    else
        conv1_dev<64, 2, 3>(bid - 25000, t1, wt_a1, b_c3, y1, 43, N1);
}

// f4: gather-y(b1) standalone (fusing it with conv2_pool cost +30us: L2 thrash)
__global__ __launch_bounds__(256) void f4_kernel(unsigned short* __restrict__ t1,
                                                 const unsigned short* __restrict__ y1,
                                                 const int* __restrict__ rowptr1,
                                                 const int* __restrict__ col1) {
    gather_dev<64, 8, 8>(blockIdx.x, t1, y1, rowptr1, col1, N1);
}

// f5: conv2_pool(b0) [2048] + conv2_pool(b1) [1024], XCD-coherent graph mapping
__global__ __launch_bounds__(256) void f5_kernel(const unsigned short* __restrict__ tb,
                                                 const unsigned short* __restrict__ wt_b0,
                                                 const float* __restrict__ b_c2,
                                                 const int* __restrict__ starts0,
                                                 unsigned short* __restrict__ p0h,
                                                 unsigned short* __restrict__ p0l,
                                                 const unsigned short* __restrict__ t1,
                                                 const unsigned short* __restrict__ wt_b1,
                                                 const float* __restrict__ b_c4,
                                                 const int* __restrict__ starts1,
                                                 unsigned short* __restrict__ p1h,
                                                 unsigned short* __restrict__ p1l) {
    int bid = blockIdx.x;
    if (bid < 2048) {
        int b = bid;
        int g = (b & 7) | ((b >> 5) << 3);
        int cb = (b >> 3) & 3;
        conv2_pool_dev<96, 3>(cb, g, tb, wt_b0, b_c2, starts0, p0h, p0l, OC0, 1920);
    } else {
        int b = bid - 2048;   // 2048 % 8 == 0 -> b mod 8 preserved
        int g = (b & 7) | ((b >> 4) << 3);
        int cb = (b >> 3) & 1;
        conv2_pool_dev<64, 2>(cb, g, t1, wt_b1, b_c4, starts1, p1h, p1l, OC1, 896);
    }
}

// f6: gemm1(b0) [256] + gemm1(b1) [256]
__global__ __launch_bounds__(256) void f6_kernel(const unsigned short* __restrict__ p0h,
                                                 const unsigned short* __restrict__ p0l,
                                                 const unsigned short* __restrict__ bt1h0,
                                                 const unsigned short* __restrict__ bt1l0,
                                                 const float* __restrict__ g0_b1,
                                                 unsigned short* __restrict__ m1h0,
                                                 unsigned short* __restrict__ m1l0,
                                                 const unsigned short* __restrict__ p1h,
                                                 const unsigned short* __restrict__ p1l,
                                                 const unsigned short* __restrict__ bt1h1,
                                                 const unsigned short* __restrict__ bt1l1,
                                                 const float* __restrict__ g1_b1,
                                                 unsigned short* __restrict__ m1h1,
                                                 unsigned short* __restrict__ m1l1) {
    int bid = blockIdx.x;
    if (bid < 256)
        gemm3x_dev<0>(bid & 15, bid >> 4, 16, p0h, p0l, bt1h0, bt1l0, g0_b1,
                      nullptr, m1h0, m1l0, 1920);
    else {
        int b = bid - 256;
        gemm3x_dev<0>(b & 15, b >> 4, 16, p1h, p1l, bt1h1, bt1l1, g1_b1,
                      nullptr, m1h1, m1l1, 896);
    }
}

// f7: gemm2(b0) [128] + gemm2(b1) [128], with fused BN-stat accumulation
__global__ __launch_bounds__(256) void f7_kernel(const unsigned short* __restrict__ m1h0,
                                                 const unsigned short* __restrict__ m1l0,
                                                 const unsigned short* __restrict__ bt2h0,
                                                 const unsigned short* __restrict__ bt2l0,
                                                 const float* __restrict__ g0_b2,
                                                 float* __restrict__ pbn0,
                                                 float* __restrict__ bnsum0,
                                                 const unsigned short* __restrict__ m1h1,
                                                 const unsigned short* __restrict__ m1l1,
                                                 const unsigned short* __restrict__ bt2h1,
                                                 const unsigned short* __restrict__ bt2l1,
                                                 const float* __restrict__ g1_b2,
                                                 float* __restrict__ pbn1,
                                                 float* __restrict__ bnsum1) {
    int bid = blockIdx.x;
    if (bid < 128)
        gemm3x_dev<3>(bid & 7, bid >> 3, 8, m1h0, m1l0, bt2h0, bt2l0, g0_b2,
                      pbn0, nullptr, nullptr, 1024, bnsum0);
    else {
        int b = bid - 128;
        gemm3x_dev<3>(b & 7, b >> 3, 8, m1h1, m1l1, bt2h1, bt2l1, g1_b2,
                      pbn1, nullptr, nullptr, 1024, bnsum1);
    }
}

// f8: coalesced BN apply (stats precomputed in f7). One block per row.
__global__ __launch_bounds__(256) void f8_kernel(const float* __restrict__ pbn0,
                                                 const float* __restrict__ bnsum0,
                                                 const float* __restrict__ g0_bn_g,
                                                 const float* __restrict__ g0_bn_b,
                                                 float* __restrict__ out_xg0,
                                                 unsigned short* __restrict__ xgh0,
                                                 unsigned short* __restrict__ xgl0,
                                                 const float* __restrict__ pbn1,
                                                 const float* __restrict__ bnsum1,
                                                 const float* __restrict__ g1_bn_g,
                                                 const float* __restrict__ g1_bn_b,
                                                 float* __restrict__ out_xg1,
                                                 unsigned short* __restrict__ xgh1,
                                                 unsigned short* __restrict__ xgl1) {
    int bid = blockIdx.x;
    int branch = bid >= 512;
    int row = branch ? bid - 512 : bid;
    const float* p   = branch ? pbn1 : pbn0;
    const float* bs  = branch ? bnsum1 : bnsum0;
    const float* gam = branch ? g1_bn_g : g0_bn_g;
    const float* bet = branch ? g1_bn_b : g0_bn_b;
    float* outp = branch ? out_xg1 : out_xg0;
    unsigned short* oh = branch ? xgh1 : xgh0;
    unsigned short* ol = branch ? xgl1 : xgl0;
    int t = threadIdx.x;
#pragma unroll
    for (int k = 0; k < 2; ++k) {
        int c = t + k * 256;
        float s = bs[c], s2 = bs[512 + c];
        float m = s * (1.f / 512.f);
        float var = s2 * (1.f / 512.f) - m * m;
        float iv = 1.f / sqrtf(var + BN_EPS);
        float x = p[(size_t)row * 512 + c];
        float v = gam[c] * (x - m) * iv + bet[c];
        outp[(size_t)row * 512 + c] = v;
        unsigned short h, l;
        split_bf(v, h, l);
        oh[(size_t)row * 512 + c] = h;
        ol[(size_t)row * 512 + c] = l;
    }
}

// f9: gemmH(b0) [64] + gemmH(b1) [64]
__global__ __launch_bounds__(256) void f9_kernel(const unsigned short* __restrict__ xgh0,
                                                 const unsigned short* __restrict__ xgl0,
                                                 const unsigned short* __restrict__ bt3h0,
                                                 const unsigned short* __restrict__ bt3l0,
                                                 const float* __restrict__ f0_b1,
                                                 float* __restrict__ hbuf0,
                                                 const unsigned short* __restrict__ xgh1,
                                                 const unsigned short* __restrict__ xgl1,
                                                 const unsigned short* __restrict__ bt3h1,
                                                 const unsigned short* __restrict__ bt3l1,
                                                 const float* __restrict__ f1_b1,
                                                 float* __restrict__ hbuf1) {
    int bid = blockIdx.x;
    if (bid < 64)
        gemm3x_dev<2>(bid & 3, bid >> 2, 4, xgh0, xgl0, bt3h0, bt3l0, f0_b1,
                      hbuf0, nullptr, nullptr, 512);
    else {
        int b = bid - 64;
        gemm3x_dev<2>(b & 3, b >> 2, 4, xgh1, xgl1, bt3h1, bt3l1, f1_b1,
                      hbuf1, nullptr, nullptr, 512);
    }
}

// f10: head2(b0) [128] + head2(b1) [128]
__global__ __launch_bounds__(256) void f10_kernel(const float* __restrict__ hbuf0,
                                                  const float* __restrict__ f0_w2,
                                                  const float* __restrict__ f0_b2,
                                                  float* __restrict__ out_z,
                                                  const float* __restrict__ hbuf1,
                                                  const float* __restrict__ f1_w2,
                                                  const float* __restrict__ f1_b2,
                                                  float* __restrict__ out_z1) {
    int bid = blockIdx.x;
    if (bid < 128)
        head2_dev(bid, hbuf0, f0_w2, f0_b2, out_z, GCONST);
    else
        head2_dev(bid - 128, hbuf1, f1_w2, f1_b2, out_z1, GCONST);
}

// ---------------------------------------------------------------------------
// launch
// ---------------------------------------------------------------------------
static inline int ceildiv(int a, int b) { return (a + b - 1) / b; }

extern "C" void kernel_launch(void* const* d_in, const int* in_sizes, int n_in,
                              void* d_out, int out_size, void* d_ws, size_t ws_size,
                              hipStream_t stream) {
    const float* x0   = (const float*)d_in[0];
    const float* x1   = (const float*)d_in[1];
    const int*   ei0  = (const int*)d_in[2];
    const int*   ei1  = (const int*)d_in[3];
    const int*   bat0 = (const int*)d_in[4];
    const int*   bat1 = (const int*)d_in[5];
    const float* w_c1 = (const float*)d_in[6];
    const float* b_c1 = (const float*)d_in[7];
    const float* w_c2 = (const float*)d_in[8];
    const float* b_c2 = (const float*)d_in[9];
    const float* w_c3 = (const float*)d_in[10];
    const float* b_c3 = (const float*)d_in[11];
    const float* w_c4 = (const float*)d_in[12];
    const float* b_c4 = (const float*)d_in[13];
    const float* g0_w1 = (const float*)d_in[14];
    const float* g0_b1 = (const float*)d_in[15];
    const float* g0_w2 = (const float*)d_in[16];
    const float* g0_b2 = (const float*)d_in[17];
    const float* g0_bn_g = (const float*)d_in[18];
    const float* g0_bn_b = (const float*)d_in[19];
    const float* g1_w1 = (const float*)d_in[20];
    const float* g1_b1 = (const float*)d_in[21];
    const float* g1_w2 = (const float*)d_in[22];
    const float* g1_b2 = (const float*)d_in[23];
    const float* g1_bn_g = (const float*)d_in[24];
    const float* g1_bn_b = (const float*)d_in[25];
    const float* f0_w1 = (const float*)d_in[26];
    const float* f0_b1 = (const float*)d_in[27];
    const float* f0_w2 = (const float*)d_in[28];
    const float* f0_b2 = (const float*)d_in[29];
    const float* f1_w1 = (const float*)d_in[30];
    const float* f1_b1 = (const float*)d_in[31];
    const float* f1_w2 = (const float*)d_in[32];
    const float* f1_b2 = (const float*)d_in[33];

    float* out = (float*)d_out;
    float* out_z   = out;
    float* out_xg0 = out + 1024;
    float* out_xg1 = out + 1024 + 262144;
    float* out_z1  = out + 1024 + 262144 + 262144;

    // workspace carve (floats; all offsets multiples of 4 -> 16B aligned)
    float* ws = (float*)d_ws;
    size_t off = 0;
    auto alloc = [&](size_t n) { float* p = ws + off; off += n; return p; };
    unsigned short* xb0 = (unsigned short*)alloc((size_t)N0 * 96 / 2); // x0 bf16; later t1 (b1 feat buf)
    unsigned short* xb1 = (unsigned short*)alloc((size_t)N1 * 64 / 2); // x1 bf16; later y1 (b1 conv1 out)
    unsigned short* tb  = (unsigned short*)alloc((size_t)N0 * 96 / 2); // staging0 overlay; b0 gather out
    unsigned short* yb  = (unsigned short*)alloc((size_t)N0 * 96 / 2); // staging1 overlay; b0 conv1 out
    unsigned short* wt_a0 = (unsigned short*)alloc(96 * 96 / 2);
    unsigned short* wt_b0 = (unsigned short*)alloc(1024 * 96 / 2);
    unsigned short* wt_a1 = (unsigned short*)alloc(48 * 64 / 2);
    unsigned short* wt_b1 = (unsigned short*)alloc(512 * 64 / 2);
    // MLP hi/lo weights, per branch
    unsigned short* bt1h0 = (unsigned short*)alloc((size_t)1024 * 1920 / 2);
    unsigned short* bt1l0 = (unsigned short*)alloc((size_t)1024 * 1920 / 2);
    unsigned short* bt2h0 = (unsigned short*)alloc((size_t)512 * 1024 / 2);
    unsigned short* bt2l0 = (unsigned short*)alloc((size_t)512 * 1024 / 2);
    unsigned short* bt3h0 = (unsigned short*)alloc((size_t)256 * 512 / 2);
    unsigned short* bt3l0 = (unsigned short*)alloc((size_t)256 * 512 / 2);
    unsigned short* bt1h1 = (unsigned short*)alloc((size_t)1024 * 896 / 2);
    unsigned short* bt1l1 = (unsigned short*)alloc((size_t)1024 * 896 / 2);
    unsigned short* bt2h1 = (unsigned short*)alloc((size_t)512 * 1024 / 2);
    unsigned short* bt2l1 = (unsigned short*)alloc((size_t)512 * 1024 / 2);
    unsigned short* bt3h1 = (unsigned short*)alloc((size_t)256 * 512 / 2);
    unsigned short* bt3l1 = (unsigned short*)alloc((size_t)256 * 512 / 2);
    // activations, per branch
    unsigned short* m1h0 = (unsigned short*)alloc((size_t)512 * 1024 / 2);
    unsigned short* m1l0 = (unsigned short*)alloc((size_t)512 * 1024 / 2);
    unsigned short* m1h1 = (unsigned short*)alloc((size_t)512 * 1024 / 2);
    unsigned short* m1l1 = (unsigned short*)alloc((size_t)512 * 1024 / 2);
    unsigned short* xgh0 = (unsigned short*)alloc((size_t)512 * 512 / 2);
    unsigned short* xgl0 = (unsigned short*)alloc((size_t)512 * 512 / 2);
    unsigned short* xgh1 = (unsigned short*)alloc((size_t)512 * 512 / 2);
    unsigned short* xgl1 = (unsigned short*)alloc((size_t)512 * 512 / 2);
    unsigned short* p0h = (unsigned short*)alloc((size_t)512 * 1920 / 2);
    unsigned short* p0l = (unsigned short*)alloc((size_t)512 * 1920 / 2);
    unsigned short* p1h = (unsigned short*)alloc((size_t)512 * 896 / 2);
    unsigned short* p1l = (unsigned short*)alloc((size_t)512 * 896 / 2);
    float* pbn0  = alloc((size_t)512 * 512);
    float* pbn1  = alloc((size_t)512 * 512);
    float* hbuf0 = alloc((size_t)512 * 256);
    float* hbuf1 = alloc((size_t)512 * 256);
    float* bnsum0 = alloc(1024);
    float* bnsum1 = alloc(1024);
    // CSR
    int* bbase2 = (int*)alloc(1024);
    int* bcur2  = (int*)alloc(1024);
    int* rowptr0 = (int*)alloc(100016);
    int* col0    = (int*)alloc(E0C);
    int* rowptr1 = (int*)alloc(100016);
    int* col1    = (int*)alloc(E1C);
    int* starts0 = (int*)alloc(520);
    int* starts1 = (int*)alloc(520);
    // staging slab overlays (NBKT*SLAB int2 = 18.8MB <= 19.2MB tb/yb regions;
    // dead after f0; tb/yb first written in f1/f2)
    int2* staging0 = (int2*)tb;
    int2* staging1 = (int2*)yb;
    // branch1 overlays (xb0/xb1 dead after their last reads in f1/f2)
    unsigned short* t1 = xb0;
    unsigned short* y1 = xb1;

    // ------------------------------ prologue ------------------------------
    misc_kernel<<<8, 256, 0, stream>>>(bat0, bat1, starts0, starts1, bcur2,
                                       bnsum0, bnsum1);
    edge_bucket2_kernel<<<3804, 256, 0, stream>>>(ei0, ei1, E0C, bcur2,
                                                  staging0, staging1,
                                                  w_c1, w_c2, w_c3, w_c4,
                                                  wt_a0, wt_b0, wt_a1, wt_b1,
                                                  p0h, p0l, p1h, p1l);
    bucket_scan2_kernel<<<2, 512, 0, stream>>>(bcur2, bbase2);
    f0_kernel<<<2 * NBKT + 50000 + 25000, 256, 0, stream>>>(
        staging0, staging1, bcur2, bbase2, rowptr0, rowptr1, col0, col1,
        xb0, x0, xb1, x1);

    // ------------------- pipelined cross-branch schedule -------------------
    f1_kernel<<<25000 + 4096, 256, 0, stream>>>(
        tb, xb0, rowptr0, col0,
        g0_w1, g0_w2, f0_w1, g1_w1, g1_w2, f1_w1,
        bt1h0, bt1l0, bt2h0, bt2l0, bt3h0, bt3l0,
        bt1h1, bt1l1, bt2h1, bt2l1, bt3h1, bt3l1);
    f2_kernel<<<25000 + 1563, 256, 0, stream>>>(t1, xb1, rowptr1, col1,
                                                tb, wt_a0, b_c1, yb);
    f3_kernel<<<25000 + 1563, 256, 0, stream>>>(tb, yb, rowptr0, col0,
                                                t1, wt_a1, b_c3, y1);
    f4_kernel<<<25000, 256, 0, stream>>>(t1, y1, rowptr1, col1);
    f5_kernel<<<2048 + 1024, 256, 0, stream>>>(tb, wt_b0, b_c2, starts0, p0h, p0l,
                                               t1, wt_b1, b_c4, starts1, p1h, p1l);
    f6_kernel<<<256 + 256, 256, 0, stream>>>(p0h, p0l, bt1h0, bt1l0, g0_b1, m1h0, m1l0,
                                             p1h, p1l, bt1h1, bt1l1, g1_b1, m1h1, m1l1);
    f7_kernel<<<128 + 128, 256, 0, stream>>>(m1h0, m1l0, bt2h0, bt2l0, g0_b2, pbn0, bnsum0,
                                             m1h1, m1l1, bt2h1, bt2l1, g1_b2, pbn1, bnsum1);
    f8_kernel<<<512 + 512, 256, 0, stream>>>(pbn0, bnsum0, g0_bn_g, g0_bn_b, out_xg0, xgh0, xgl0,
                                             pbn1, bnsum1, g1_bn_g, g1_bn_b, out_xg1, xgh1, xgl1);
    f9_kernel<<<64 + 64, 256, 0, stream>>>(xgh0, xgl0, bt3h0, bt3l0, f0_b1, hbuf0,
                                           xgh1, xgl1, bt3h1, bt3l1, f1_b1, hbuf1);
    f10_kernel<<<128 + 128, 256, 0, stream>>>(hbuf0, f0_w2, f0_b2, out_z,
                                              hbuf1, f1_w2, f1_b2, out_z1);
}